// Round 5
// baseline (752.276 us; speedup 1.0000x reference)
//
#include <hip/hip_runtime.h>
#include <hip/hip_bf16.h>
#include <math.h>

typedef __attribute__((ext_vector_type(8))) short short8;
typedef __attribute__((ext_vector_type(16))) float floatx16;
using bf16_t = __hip_bfloat16;

#define GLOAD16(gp, lp)                                                        \
  __builtin_amdgcn_global_load_lds(                                            \
      (const __attribute__((address_space(1))) unsigned int*)(gp),             \
      (__attribute__((address_space(3))) unsigned int*)(lp), 16, 0, 0)

#define CFENCE() asm volatile("" ::: "memory")
#define BAR()                                                                  \
  do {                                                                         \
    CFENCE();                                                                  \
    __builtin_amdgcn_s_barrier();                                              \
    CFENCE();                                                                  \
  } while (0)

// ---------------------------------------------------------------- converts --
__global__ void convert_f32_to_bf16(const float* __restrict__ in,
                                    bf16_t* __restrict__ out) {
  int i = blockIdx.x * 256 + threadIdx.x;  // 4 elements per thread
  float4 v = ((const float4*)in)[i];
  union { ushort4 u; bf16_t b[4]; } pk;
  pk.b[0] = __float2bfloat16(v.x);
  pk.b[1] = __float2bfloat16(v.y);
  pk.b[2] = __float2bfloat16(v.z);
  pk.b[3] = __float2bfloat16(v.w);
  ((ushort4*)out)[i] = pk.u;
}

// out[c][r] = bf16(in[r][c]), both 4096x4096. float4 loads, ushort4 stores.
__global__ void transpose_f32_bf16(const float* __restrict__ in,
                                   bf16_t* __restrict__ out) {
  __shared__ float t[64][65];
  const int r0 = blockIdx.y * 64, c0 = blockIdx.x * 64;
  const int tid = threadIdx.x;
  const int c4 = tid & 15, rr = tid >> 4;
#pragma unroll
  for (int i = 0; i < 4; ++i) {
    const int r = rr + i * 16;
    float4 v = *(const float4*)(in + (size_t)(r0 + r) * 4096 + c0 + c4 * 4);
    t[c4 * 4 + 0][r] = v.x;
    t[c4 * 4 + 1][r] = v.y;
    t[c4 * 4 + 2][r] = v.z;
    t[c4 * 4 + 3][r] = v.w;
  }
  __syncthreads();
  const int r4 = tid & 15, cc = tid >> 4;
#pragma unroll
  for (int i = 0; i < 4; ++i) {
    const int c = cc + i * 16;
    union { ushort4 u; bf16_t b[4]; } pk;
#pragma unroll
    for (int j = 0; j < 4; ++j) pk.b[j] = __float2bfloat16(t[c][r4 * 4 + j]);
    *(ushort4*)(out + (size_t)(c0 + c) * 4096 + r0 + r4 * 4) = pk.u;
  }
}

// ---------------------------------------------------------------- NT GEMM ---
// C[m][n] = sum_k A[m][k]*B[n][k]; 4096^3, bf16 K-fastest operands.
// 256x256 tile, 8 waves (2Mx4N), wave tile 128x64 = 4x2 subtiles of 32x32.
// MFMA: v_mfma_f32_32x32x16_bf16 (higher ceiling than 16x16x32).
// LDS: ring of 4 K=32 planes per operand (8 x 16KB = 128 KiB). Per region:
//   {4x global_load_lds (plane r+3); 12x ds_read_b128; setprio(1); 16 MFMA;
//    setprio(0); vmcnt(8); s_barrier}  (one barrier, counted vmcnt)
// Plane layout: pair p=row>>1 at p*64 elems, 8 slots of 8 bf16,
// phys = ((row&1)*4 + (k>>3)) ^ (p&7)  -> conflict-limited ds_read_b128.
// XCD swizzle: swz=(bid&7)*32 + bid>>3 -> each XCD shares 2 A-panels (4MB L2).
// EPI 0: C=bf16(acc)
// EPI 2: C=bf16(X0[m][n] + relu(acc)*mask[m])
// EPI 3: fused M5+pool: partialS/partialM per (by, col) of
//        v = satt[r]*relu(acc+lnb[c])*mask[r]  (no dense output!)
// EPI 4: C=bf16(relu(acc)*mask[m]) AND AUX = C^T (LDS-staged transpose)

#define REGION(R, S)                                                           \
  {                                                                            \
    const int h3 = ((R) + 3) & 127;                                            \
    const size_t ko = (size_t)h3 * 32;                                         \
    bf16_t* dA = smem + (((R) + 3) & 3) * 8192 + wave * 512;                   \
    bf16_t* dB = smem + 32768 + (((R) + 3) & 3) * 8192 + wave * 512;           \
    GLOAD16(A + gAc0 + ko, dA);                                                \
    GLOAD16(A + gAc1 + ko, dA + 4096);                                         \
    GLOAD16(B + gBc0 + ko, dB);                                                \
    GLOAD16(B + gBc1 + ko, dB + 4096);                                         \
    const bf16_t* sA = smem + (S) * 8192;                                      \
    const bf16_t* sB = smem + 32768 + (S) * 8192;                              \
    short8 aF[4][2], bF[2][2];                                                 \
    _Pragma("unroll") for (int ks = 0; ks < 2; ++ks) {                         \
      _Pragma("unroll") for (int n = 0; n < 2; ++n)                            \
          bF[n][ks] = *(const short8*)(sB + offB[n][ks]);                      \
      _Pragma("unroll") for (int m = 0; m < 4; ++m)                            \
          aF[m][ks] = *(const short8*)(sA + offA[m][ks]);                      \
    }                                                                          \
    __builtin_amdgcn_s_setprio(1);                                             \
    _Pragma("unroll") for (int ks = 0; ks < 2; ++ks)                           \
        _Pragma("unroll") for (int m = 0; m < 4; ++m)                          \
            _Pragma("unroll") for (int n = 0; n < 2; ++n)                      \
                acc[m][n] = __builtin_amdgcn_mfma_f32_32x32x16_bf16(           \
                    aF[m][ks], bF[n][ks], acc[m][n], 0, 0, 0);                 \
    __builtin_amdgcn_s_setprio(0);                                             \
    asm volatile("s_waitcnt vmcnt(8)" ::: "memory");                           \
    BAR();                                                                     \
  }

template <int EPI>
__global__ __launch_bounds__(512, 2) void gemm_nt(
    const bf16_t* __restrict__ A, const bf16_t* __restrict__ B,
    void* __restrict__ C, void* __restrict__ AUX,
    const bf16_t* __restrict__ X0, const float* __restrict__ rowm,
    const float* __restrict__ satt, const float* __restrict__ lnb) {
  extern __shared__ bf16_t smem[];  // 8 planes x 8192 elems = 128 KiB
  const int tid = threadIdx.x;
  const int wave = tid >> 6, lane = tid & 63;
  const int bid = blockIdx.x;
  const int swz = ((bid & 7) << 5) | (bid >> 3);  // XCD-aware remap
  const int by = swz >> 4, bx = swz & 15;
  const int m0 = by * 256, n0 = bx * 256;
  const int wr = wave >> 2, wc = wave & 3;  // 2M x 4N wave grid

  floatx16 acc[4][2] = {};

  // ---- staging source addressing (pre-swizzled global; linear LDS dest).
  const int pr = tid >> 3, ph = tid & 7;
  const int sl8 = ph ^ (pr & 7);                 // logical slot8
  const int rl = (pr << 1) + (sl8 >> 2);         // local row in 128-row call
  const int colg = (sl8 & 3) << 3;               // k element offset (0..24)
  const size_t gAc0 = (size_t)(m0 + rl) * 4096 + colg;
  const size_t gAc1 = gAc0 + (size_t)128 * 4096;
  const size_t gBc0 = (size_t)(n0 + rl) * 4096 + colg;
  const size_t gBc1 = gBc0 + (size_t)128 * 4096;

  // ---- ds_read addressing for 32x32x16 fragments:
  // lane holds op[row = l&31][k = (l>>5)*8 + j]; per kstep ks, slot = ks*2+hi.
  // row r -> pair p = r>>1, phys = ((r&1)*4 + slot) ^ (p&7); bases are
  // multiples of 8 pairs so p&7 = (l31>>1)&7.
  const int l31 = lane & 31, hi = lane >> 5;
  const int x7 = (l31 >> 1) & 7;
  const int rp4 = (l31 & 1) << 2;
  int offA[4][2], offB[2][2];
#pragma unroll
  for (int m = 0; m < 4; ++m)
#pragma unroll
    for (int ks = 0; ks < 2; ++ks)
      offA[m][ks] = (wr * 64 + m * 16 + (l31 >> 1)) * 64 +
                    (((rp4 + ks * 2 + hi) ^ x7) << 3);
#pragma unroll
  for (int n = 0; n < 2; ++n)
#pragma unroll
    for (int ks = 0; ks < 2; ++ks)
      offB[n][ks] = (wc * 32 + n * 16 + (l31 >> 1)) * 64 +
                    (((rp4 + ks * 2 + hi) ^ x7) << 3);

  // ---- prologue: stage planes 0,1,2 into ring slots 0,1,2
#pragma unroll
  for (int p = 0; p < 3; ++p) {
    bf16_t* dA = smem + p * 8192 + wave * 512;
    bf16_t* dB = smem + 32768 + p * 8192 + wave * 512;
    const size_t ko = (size_t)p * 32;
    GLOAD16(A + gAc0 + ko, dA);
    GLOAD16(A + gAc1 + ko, dA + 4096);
    GLOAD16(B + gBc0 + ko, dB);
    GLOAD16(B + gBc1 + ko, dB + 4096);
  }
  asm volatile("s_waitcnt vmcnt(8)" ::: "memory");
  BAR();

  for (int r = 0; r < 128; r += 4) {
    REGION(r, 0)
    REGION(r + 1, 1)
    REGION(r + 2, 2)
    REGION(r + 3, 3)
  }
  asm volatile("s_waitcnt vmcnt(0)" ::: "memory");
  BAR();  // ring LDS now safe to reuse

  // epilogue: D mapping col = lane&31, row = (q&3) + 8*(q>>2) + 4*hi
  const int wmr = wr * 128, wnc = wc * 64;
  bf16_t* Cb = (bf16_t*)C;

  if constexpr (EPI == 3) {
    // fused: v = satt[r]*relu(acc+lnb[c])*mask[r]; column partial sum & max
    const int gc0 = n0 + wnc + l31;
    const float lb0 = lnb[gc0], lb1 = lnb[gc0 + 32];
    float s0 = 0.f, s1 = 0.f, mx0 = 0.f, mx1 = 0.f;
#pragma unroll
    for (int m = 0; m < 4; ++m) {
#pragma unroll
      for (int q = 0; q < 16; ++q) {
        const int row = (q & 3) + 8 * (q >> 2) + 4 * hi;
        const int gr = m0 + wmr + m * 32 + row;
        const float f = satt[gr] * rowm[gr];
        const float v0 = fmaxf(acc[m][0][q] + lb0, 0.f) * f;
        const float v1 = fmaxf(acc[m][1][q] + lb1, 0.f) * f;
        s0 += v0; s1 += v1;
        mx0 = fmaxf(mx0, v0); mx1 = fmaxf(mx1, v1);
      }
    }
    s0 += __shfl_xor(s0, 32); s1 += __shfl_xor(s1, 32);
    mx0 = fmaxf(mx0, __shfl_xor(mx0, 32));
    mx1 = fmaxf(mx1, __shfl_xor(mx1, 32));
    float* sred = (float*)smem;        // [2][256]
    float* mred = sred + 512;          // [2][256]
    if (hi == 0) {
      const int c256 = wc * 64 + l31;
      sred[wr * 256 + c256] = s0;
      sred[wr * 256 + c256 + 32] = s1;
      mred[wr * 256 + c256] = mx0;
      mred[wr * 256 + c256 + 32] = mx1;
    }
    __syncthreads();
    if (tid < 256) {
      const float S = sred[tid] + sred[256 + tid];
      const float MX = fmaxf(mred[tid], mred[256 + tid]);
      ((float*)C)[(size_t)by * 4096 + n0 + tid] = S;    // partial sums
      ((float*)AUX)[(size_t)by * 4096 + n0 + tid] = MX; // partial maxes
    }
    return;
  }

  bf16_t* myT = smem + wave * 8192;  // EPI4: 64 cols x 128 rows, XOR-swizzled
#pragma unroll
  for (int m = 0; m < 4; ++m) {
#pragma unroll
    for (int n = 0; n < 2; ++n) {
#pragma unroll
      for (int q = 0; q < 16; ++q) {
        const int row = (q & 3) + 8 * (q >> 2) + 4 * hi;
        const int gr = m0 + wmr + m * 32 + row;
        const int gc = n0 + wnc + n * 32 + l31;
        float v = acc[m][n][q];
        const size_t idx = (size_t)gr * 4096 + gc;
        if constexpr (EPI == 0) {
          Cb[idx] = __float2bfloat16(v);
        } else if constexpr (EPI == 2) {
          v = __bfloat162float(X0[idx]) + fmaxf(v, 0.f) * rowm[gr];
          Cb[idx] = __float2bfloat16(v);
        } else {  // EPI 4: relu*mask, write C and stage C^T in LDS
          v = fmaxf(v, 0.f) * rowm[gr];
          const bf16_t bv = __float2bfloat16(v);
          Cb[idx] = bv;
          const int lrow = m * 32 + row;     // 0..127
          const int lcol = n * 32 + l31;     // 0..63
          myT[lcol * 128 + (lrow ^ ((lcol & 15) << 3))] = bv;
        }
      }
    }
  }
  if constexpr (EPI == 4) {
    bf16_t* CT = (bf16_t*)AUX;
#pragma unroll
    for (int i = 0; i < 16; ++i) {
      const int chunkid = i * 64 + lane;  // 0..1023
      const int lcol = chunkid >> 4;      // 0..63
      const int a8 = chunkid & 15;        // token chunk
      const int lbase = lcol * 128 + ((a8 * 8) ^ ((lcol & 15) << 3));
      short8 vv = *(const short8*)(myT + lbase);
      *(short8*)(CT + (size_t)(n0 + wnc + lcol) * 4096 + (m0 + wmr) + a8 * 8) =
          vv;
    }
  }
}

// ---------------------------------------------------------------- smalls ----
__global__ void att_kernel(const bf16_t* __restrict__ x,
                           const float* __restrict__ aw,
                           const float* __restrict__ ab,
                           float* __restrict__ satt) {
  const int row = blockIdx.x, tid = threadIdx.x;
  float s = 0.f;
  const bf16_t* xr = x + (size_t)row * 4096 + tid * 16;
#pragma unroll
  for (int h = 0; h < 2; ++h) {
    short8 v = *(const short8*)(xr + h * 8);
#pragma unroll
    for (int j = 0; j < 8; ++j) {
      union { unsigned int u; float f; } cv;
      cv.u = ((unsigned int)(unsigned short)v[j]) << 16;
      s += cv.f * aw[tid * 16 + h * 8 + j];
    }
  }
  __shared__ float red[256];
  red[tid] = s;
  __syncthreads();
  for (int st = 128; st > 0; st >>= 1) {
    if (tid < st) red[tid] += red[tid + st];
    __syncthreads();
  }
  if (tid == 0) satt[row] = 1.f / (1.f + expf(-(red[0] + ab[0])));
}

__global__ void final_kernel(const float* __restrict__ pS,
                             const float* __restrict__ pM,
                             const float* __restrict__ pw,
                             const float* __restrict__ pb,
                             float* __restrict__ out) {
  const int b = blockIdx.x, tid = threadIdx.x;
  float a[20];
#pragma unroll
  for (int k = 0; k < 20; ++k) a[k] = 0.f;
  for (int c = tid; c < 4096; c += 256) {
    const size_t i0 = (size_t)(2 * b) * 4096 + c;
    const size_t i1 = (size_t)(2 * b + 1) * 4096 + c;
    const float s = pS[i0] + pS[i1];
    const float mx = fmaxf(pM[i0], pM[i1]);
    const float v = s * mx;
#pragma unroll
    for (int k = 0; k < 20; ++k) a[k] += v * pw[c * 20 + k];
  }
  __shared__ float red[256][20];
#pragma unroll
  for (int k = 0; k < 20; ++k) red[tid][k] = a[k];
  __syncthreads();
  for (int st = 128; st > 0; st >>= 1) {
    if (tid < st)
      for (int k = 0; k < 20; ++k) red[tid][k] += red[tid + st][k];
    __syncthreads();
  }
  if (tid < 20) out[b * 20 + tid] = red[0][tid] + pb[tid];
}

// ---------------------------------------------------------------- launch ----
extern "C" void kernel_launch(void* const* d_in, const int* in_sizes, int n_in,
                              void* d_out, int out_size, void* d_ws,
                              size_t ws_size, hipStream_t stream) {
  const float* inputs = (const float*)d_in[0];
  const float* adj    = (const float*)d_in[1];
  const float* mask   = (const float*)d_in[2];
  const float* W0     = (const float*)d_in[3];
  const float* W1     = (const float*)d_in[4];
  const float* att_w  = (const float*)d_in[5];
  const float* att_b  = (const float*)d_in[6];
  const float* ln_w   = (const float*)d_in[7];
  const float* ln_b   = (const float*)d_in[8];
  const float* pred_w = (const float*)d_in[9];
  const float* pred_b = (const float*)d_in[10];
  float* out = (float*)d_out;

  const size_t MB32 = (size_t)32 * 1024 * 1024;
  char* ws = (char*)d_ws;
  bf16_t* SLOT0 = (bf16_t*)(ws);             // XT -> x0T -> x
  bf16_t* SLOT1 = (bf16_t*)(ws + MB32);      // W0T -> W1T -> ln_wT
  bf16_t* SLOT2 = (bf16_t*)(ws + 2 * MB32);  // adjb
  bf16_t* SLOT3 = (bf16_t*)(ws + 3 * MB32);  // S0T -> S1T
  bf16_t* SLOT4 = (bf16_t*)(ws + 4 * MB32);  // x0
  float*  pS    = (float*)(ws + 5 * MB32);                 // [16][4096]
  float*  pM    = (float*)(ws + 5 * MB32 + 256 * 1024);    // [16][4096]
  float*  satt  = (float*)(ws + 5 * MB32 + 512 * 1024);    // [4096]

  const int SMEM = 131072;
  (void)hipFuncSetAttribute((const void*)gemm_nt<0>,
                            hipFuncAttributeMaxDynamicSharedMemorySize, SMEM);
  (void)hipFuncSetAttribute((const void*)gemm_nt<2>,
                            hipFuncAttributeMaxDynamicSharedMemorySize, SMEM);
  (void)hipFuncSetAttribute((const void*)gemm_nt<3>,
                            hipFuncAttributeMaxDynamicSharedMemorySize, SMEM);
  (void)hipFuncSetAttribute((const void*)gemm_nt<4>,
                            hipFuncAttributeMaxDynamicSharedMemorySize, SMEM);

  const dim3 gT(64, 64);

  // M1: S0T = XT (.) W0T
  transpose_f32_bf16<<<gT, 256, 0, stream>>>(inputs, SLOT0);
  transpose_f32_bf16<<<gT, 256, 0, stream>>>(W0, SLOT1);
  convert_f32_to_bf16<<<16384, 256, 0, stream>>>(adj, SLOT2);
  gemm_nt<0><<<256, 512, SMEM, stream>>>(SLOT0, SLOT1, SLOT3, nullptr, nullptr,
                                         nullptr, nullptr, nullptr);
  // M2: x0 = relu(adjb (.) S0T) * mask[row]; fused x0T write
  gemm_nt<4><<<256, 512, SMEM, stream>>>(SLOT2, SLOT3, SLOT4, SLOT0, nullptr,
                                         mask, nullptr, nullptr);
  // W1T
  transpose_f32_bf16<<<gT, 256, 0, stream>>>(W1, SLOT1);
  // M3: S1T = x0T (.) W1T
  gemm_nt<0><<<256, 512, SMEM, stream>>>(SLOT0, SLOT1, SLOT3, nullptr, nullptr,
                                         nullptr, nullptr, nullptr);
  // M4: x = x0 + relu(adjb (.) S1T) * mask[row]
  gemm_nt<2><<<256, 512, SMEM, stream>>>(SLOT2, SLOT3, SLOT0, nullptr, SLOT4,
                                         mask, nullptr, nullptr);
  // soft_att from x
  att_kernel<<<4096, 256, 0, stream>>>(SLOT0, att_w, att_b, satt);
  // ln_wT
  transpose_f32_bf16<<<gT, 256, 0, stream>>>(ln_w, SLOT1);
  // M5 fused with pool partials: per-block column sum/max of gated h
  gemm_nt<3><<<256, 512, SMEM, stream>>>(SLOT0, SLOT1, pS, pM, nullptr,
                                         mask, satt, ln_b);
  // out[b] = ((sum0+sum1)*(max(max0,max1))) @ pred_w + pred_b
  final_kernel<<<8, 256, 0, stream>>>(pS, pM, pred_w, pred_b, out);
}

// Round 6
// 671.376 us; speedup vs baseline: 1.1205x; 1.1205x over previous
//
#include <hip/hip_runtime.h>
#include <hip/hip_bf16.h>
#include <math.h>

typedef __attribute__((ext_vector_type(8))) short short8;
typedef __attribute__((ext_vector_type(4))) float floatx4;
using bf16_t = __hip_bfloat16;

#define GLOAD16(gp, lp)                                                        \
  __builtin_amdgcn_global_load_lds(                                            \
      (const __attribute__((address_space(1))) unsigned int*)(gp),             \
      (__attribute__((address_space(3))) unsigned int*)(lp), 16, 0, 0)

#define CFENCE() asm volatile("" ::: "memory")
#define BAR()                                                                  \
  do {                                                                         \
    CFENCE();                                                                  \
    __builtin_amdgcn_s_barrier();                                              \
    CFENCE();                                                                  \
  } while (0)

// ---------------------------------------------------------------- converts --
__global__ void convert_f32_to_bf16(const float* __restrict__ in,
                                    bf16_t* __restrict__ out) {
  int i = blockIdx.x * 256 + threadIdx.x;  // 4 elements per thread
  float4 v = ((const float4*)in)[i];
  union { ushort4 u; bf16_t b[4]; } pk;
  pk.b[0] = __float2bfloat16(v.x);
  pk.b[1] = __float2bfloat16(v.y);
  pk.b[2] = __float2bfloat16(v.z);
  pk.b[3] = __float2bfloat16(v.w);
  ((ushort4*)out)[i] = pk.u;
}

// out[c][r] = bf16(in[r][c]), both 4096x4096. float4 loads, ushort4 stores.
__global__ void transpose_f32_bf16(const float* __restrict__ in,
                                   bf16_t* __restrict__ out) {
  __shared__ float t[64][65];
  const int r0 = blockIdx.y * 64, c0 = blockIdx.x * 64;
  const int tid = threadIdx.x;
  const int c4 = tid & 15, rr = tid >> 4;
#pragma unroll
  for (int i = 0; i < 4; ++i) {
    const int r = rr + i * 16;
    float4 v = *(const float4*)(in + (size_t)(r0 + r) * 4096 + c0 + c4 * 4);
    t[c4 * 4 + 0][r] = v.x;
    t[c4 * 4 + 1][r] = v.y;
    t[c4 * 4 + 2][r] = v.z;
    t[c4 * 4 + 3][r] = v.w;
  }
  __syncthreads();
  const int r4 = tid & 15, cc = tid >> 4;
#pragma unroll
  for (int i = 0; i < 4; ++i) {
    const int c = cc + i * 16;
    union { ushort4 u; bf16_t b[4]; } pk;
#pragma unroll
    for (int j = 0; j < 4; ++j) pk.b[j] = __float2bfloat16(t[c][r4 * 4 + j]);
    *(ushort4*)(out + (size_t)(c0 + c) * 4096 + r0 + r4 * 4) = pk.u;
  }
}

// ---------------------------------------------------------------- NT GEMM ---
// C[m][n] = sum_k A[m][k]*B[n][k]; 4096^3, bf16 K-fastest operands.
// 256x256 tile, 8 waves (2Mx4N), wave tile 128x64, 16x16x32 MFMA (proven
// conflict-free fragment layout). LDS: ring-5 of K=32 planes per operand
// (10 x 16KB = 160 KiB). Logical iter = K=64 (two planes). 4 phases/iter
// (m201 quadrant rotation; reads only the operand-half that changes):
//  P0: read A-half0(8) + B-half0(4); stage A(2t+3); BAR; 16 MFMA; BAR
//  P1: read B-half1(4);              stage B(2t+3); BAR; 16 MFMA; BAR
//  P2: read A-half1(8);              stage A(2t+4); BAR; 16 MFMA; BAR
//  P3: (no reads, bF cached);        stage B(2t+4); BAR; 16 MFMA; vmcnt(4); BAR
// Counted vmcnt(4): plane 2t+3 drained (needed next iter), plane 2t+4 in
// flight. Pair-XOR swizzle (phys8 = slot8 ^ (pair&7)) conflict-free reads.
// XCD swizzle: swz=(bid&7)*32 + bid>>3.
// EPI 0: C=bf16(acc)
// EPI 2: C=bf16(X0[m][n] + relu(acc)*mask[m])
// EPI 3: fused M5+pool: per-(by,col) partial sum/max of
//        satt[r]*relu(acc+lnb[c])*mask[r]  (no dense output)
// EPI 4: C=bf16(relu(acc)*mask[m]) AND AUX = C^T (LDS-staged transpose)

#define PH_TAIL_NONE
#define PH_TAIL_VM asm volatile("s_waitcnt vmcnt(4)" ::: "memory");

#define ITER(T, S0, S1, S3, S4)                                                \
  {                                                                            \
    const int t_ = (T);                                                        \
    const bf16_t* sA0 = smem + (S0) * 8192;                                    \
    const bf16_t* sA1 = smem + (S1) * 8192;                                    \
    const bf16_t* sB0 = smem + 40960 + (S0) * 8192;                            \
    const bf16_t* sB1 = smem + 40960 + (S1) * 8192;                            \
    bf16_t* dA3 = smem + (S3) * 8192 + wave * 512;                             \
    bf16_t* dB3 = smem + 40960 + (S3) * 8192 + wave * 512;                     \
    bf16_t* dA4 = smem + (S4) * 8192 + wave * 512;                             \
    bf16_t* dB4 = smem + 40960 + (S4) * 8192 + wave * 512;                     \
    const size_t ko3 = (size_t)(((2 * t_ + 3) & 127) * 32);                    \
    const size_t ko4 = (size_t)(((2 * t_ + 4) & 127) * 32);                    \
    short8 aF[4][2], bF[2][2], bG[2][2];                                       \
    /* ---- P0 */                                                              \
    _Pragma("unroll") for (int n = 0; n < 2; ++n) {                            \
      bF[n][0] = *(const short8*)(sB0 + offB_e + n * 512);                     \
      bF[n][1] = *(const short8*)(sB1 + offB_e + n * 512);                     \
    }                                                                          \
    _Pragma("unroll") for (int m = 0; m < 4; ++m) {                            \
      aF[m][0] = *(const short8*)(sA0 + offA_e + m * 512);                     \
      aF[m][1] = *(const short8*)(sA1 + offA_e + m * 512);                     \
    }                                                                          \
    GLOAD16(A + gAc0 + ko3, dA3);                                              \
    GLOAD16(A + gAc1 + ko3, dA3 + 4096);                                       \
    BAR();                                                                     \
    __builtin_amdgcn_s_setprio(1);                                             \
    _Pragma("unroll") for (int pl = 0; pl < 2; ++pl)                           \
        _Pragma("unroll") for (int m = 0; m < 4; ++m)                          \
            _Pragma("unroll") for (int n = 0; n < 2; ++n)                      \
                acc[m][n] = __builtin_amdgcn_mfma_f32_16x16x32_bf16(           \
                    aF[m][pl], bF[n][pl], acc[m][n], 0, 0, 0);                 \
    __builtin_amdgcn_s_setprio(0);                                             \
    BAR();                                                                     \
    /* ---- P1 */                                                              \
    _Pragma("unroll") for (int n = 0; n < 2; ++n) {                            \
      bG[n][0] = *(const short8*)(sB0 + offB_e + (2 + n) * 512);               \
      bG[n][1] = *(const short8*)(sB1 + offB_e + (2 + n) * 512);               \
    }                                                                          \
    GLOAD16(B + gBc0 + ko3, dB3);                                              \
    GLOAD16(B + gBc1 + ko3, dB3 + 4096);                                       \
    BAR();                                                                     \
    __builtin_amdgcn_s_setprio(1);                                             \
    _Pragma("unroll") for (int pl = 0; pl < 2; ++pl)                           \
        _Pragma("unroll") for (int m = 0; m < 4; ++m)                          \
            _Pragma("unroll") for (int n = 0; n < 2; ++n)                      \
                acc[m][2 + n] = __builtin_amdgcn_mfma_f32_16x16x32_bf16(       \
                    aF[m][pl], bG[n][pl], acc[m][2 + n], 0, 0, 0);             \
    __builtin_amdgcn_s_setprio(0);                                             \
    BAR();                                                                     \
    /* ---- P2 */                                                              \
    _Pragma("unroll") for (int m = 0; m < 4; ++m) {                            \
      aF[m][0] = *(const short8*)(sA0 + offA_e + (4 + m) * 512);               \
      aF[m][1] = *(const short8*)(sA1 + offA_e + (4 + m) * 512);               \
    }                                                                          \
    GLOAD16(A + gAc0 + ko4, dA4);                                              \
    GLOAD16(A + gAc1 + ko4, dA4 + 4096);                                       \
    BAR();                                                                     \
    __builtin_amdgcn_s_setprio(1);                                             \
    _Pragma("unroll") for (int pl = 0; pl < 2; ++pl)                           \
        _Pragma("unroll") for (int m = 0; m < 4; ++m)                          \
            _Pragma("unroll") for (int n = 0; n < 2; ++n)                      \
                acc[4 + m][2 + n] = __builtin_amdgcn_mfma_f32_16x16x32_bf16(   \
                    aF[m][pl], bG[n][pl], acc[4 + m][2 + n], 0, 0, 0);         \
    __builtin_amdgcn_s_setprio(0);                                             \
    BAR();                                                                     \
    /* ---- P3 (no ds_reads; bF cached) */                                     \
    GLOAD16(B + gBc0 + ko4, dB4);                                              \
    GLOAD16(B + gBc1 + ko4, dB4 + 4096);                                       \
    BAR();                                                                     \
    __builtin_amdgcn_s_setprio(1);                                             \
    _Pragma("unroll") for (int pl = 0; pl < 2; ++pl)                           \
        _Pragma("unroll") for (int m = 0; m < 4; ++m)                          \
            _Pragma("unroll") for (int n = 0; n < 2; ++n)                      \
                acc[4 + m][n] = __builtin_amdgcn_mfma_f32_16x16x32_bf16(       \
                    aF[m][pl], bF[n][pl], acc[4 + m][n], 0, 0, 0);             \
    __builtin_amdgcn_s_setprio(0);                                             \
    asm volatile("s_waitcnt vmcnt(4)" ::: "memory");                           \
    BAR();                                                                     \
  }

template <int EPI>
__global__ __launch_bounds__(512, 2) void gemm_nt(
    const bf16_t* __restrict__ A, const bf16_t* __restrict__ B,
    void* __restrict__ C, void* __restrict__ AUX,
    const bf16_t* __restrict__ X0, const float* __restrict__ rowm,
    const float* __restrict__ satt, const float* __restrict__ lnb) {
  extern __shared__ bf16_t smem[];  // 10 planes x 8192 elems = 160 KiB
  const int tid = threadIdx.x;
  const int wave = tid >> 6, lane = tid & 63;
  const int bid = blockIdx.x;
  const int swz = ((bid & 7) << 5) | (bid >> 3);  // XCD-aware remap
  const int by = swz >> 4, bx = swz & 15;
  const int m0 = by * 256, n0 = bx * 256;
  const int wr = wave >> 2, wc = wave & 3;  // 2M x 4N wave grid

  floatx4 acc[8][4] = {};

  // ---- staging source addressing (pre-swizzled global; linear LDS dest).
  const int pr = tid >> 3, ph = tid & 7;
  const int sl8 = ph ^ (pr & 7);                 // logical slot8
  const int rl = (pr << 1) + (sl8 >> 2);         // local row in 128-row call
  const int colg = (sl8 & 3) << 3;               // k element offset (0..24)
  const size_t gAc0 = (size_t)(m0 + rl) * 4096 + colg;
  const size_t gAc1 = gAc0 + (size_t)128 * 4096;
  const size_t gBc0 = (size_t)(n0 + rl) * 4096 + colg;
  const size_t gBc1 = gBc0 + (size_t)128 * 4096;

  // ---- ds_read addressing (16x16x32 frags; proven conflict-free):
  // row16 = lane&15, kslot = lane>>4; phys = (rowpar*4 + kslot) ^ (pair&7)
  const int l15 = lane & 15;
  const int phRd = (((lane & 1) << 2) + (lane >> 4)) ^ (l15 >> 1);
  const int offA_e = (wr * 64 + (l15 >> 1)) * 64 + phRd * 8;  // + m*512
  const int offB_e = (wc * 32 + (l15 >> 1)) * 64 + phRd * 8;  // + n*512

  // ---- prologue: stage planes 0,1,2 into slots 0,1,2 (12 loads)
#pragma unroll
  for (int p = 0; p < 3; ++p) {
    bf16_t* dA = smem + p * 8192 + wave * 512;
    bf16_t* dB = smem + 40960 + p * 8192 + wave * 512;
    const size_t ko = (size_t)p * 32;
    GLOAD16(A + gAc0 + ko, dA);
    GLOAD16(A + gAc1 + ko, dA + 4096);
    GLOAD16(B + gBc0 + ko, dB);
    GLOAD16(B + gBc1 + ko, dB + 4096);
  }
  asm volatile("s_waitcnt vmcnt(4)" ::: "memory");
  BAR();

  for (int tb = 0; tb < 64; tb += 5) {
    ITER(tb, 0, 1, 3, 4)
    ITER(tb + 1, 2, 3, 0, 1)
    ITER(tb + 2, 4, 0, 2, 3)
    ITER(tb + 3, 1, 2, 4, 0)
    if (tb + 4 < 64) ITER(tb + 4, 3, 4, 1, 2)
  }
  asm volatile("s_waitcnt vmcnt(0)" ::: "memory");
  BAR();  // LDS now safe to reuse

  // epilogue: D lane mapping col = lane&15, row = (lane>>4)*4 + u
  const int wmr = wr * 128, wnc = wc * 64;
  const int rr = (lane >> 4) * 4, cc = lane & 15;
  bf16_t* Cb = (bf16_t*)C;

  if constexpr (EPI == 3) {
    // fused: v = satt[r]*relu(acc+lnb[c])*mask[r]; column partial sum & max
    float lb[4];
#pragma unroll
    for (int n = 0; n < 4; ++n) lb[n] = lnb[n0 + wnc + n * 16 + cc];
    float s[4] = {0.f, 0.f, 0.f, 0.f}, mx[4] = {0.f, 0.f, 0.f, 0.f};
#pragma unroll
    for (int m = 0; m < 8; ++m) {
#pragma unroll
      for (int u = 0; u < 4; ++u) {
        const int gr = m0 + wmr + m * 16 + rr + u;
        const float f = satt[gr] * rowm[gr];
#pragma unroll
        for (int n = 0; n < 4; ++n) {
          const float v = fmaxf(acc[m][n][u] + lb[n], 0.f) * f;
          s[n] += v;
          mx[n] = fmaxf(mx[n], v);
        }
      }
    }
#pragma unroll
    for (int n = 0; n < 4; ++n) {
      s[n] += __shfl_xor(s[n], 16);
      s[n] += __shfl_xor(s[n], 32);
      mx[n] = fmaxf(mx[n], __shfl_xor(mx[n], 16));
      mx[n] = fmaxf(mx[n], __shfl_xor(mx[n], 32));
    }
    float* sred = (float*)smem;  // [2][256]
    float* mred = sred + 512;    // [2][256]
    if ((lane >> 4) == 0) {
#pragma unroll
      for (int n = 0; n < 4; ++n) {
        sred[wr * 256 + wnc + n * 16 + cc] = s[n];
        mred[wr * 256 + wnc + n * 16 + cc] = mx[n];
      }
    }
    __syncthreads();
    if (tid < 256) {
      const float S = sred[tid] + sred[256 + tid];
      const float MX = fmaxf(mred[tid], mred[256 + tid]);
      ((float*)C)[(size_t)by * 4096 + n0 + tid] = S;     // partial sums
      ((float*)AUX)[(size_t)by * 4096 + n0 + tid] = MX;  // partial maxes
    }
    return;
  }

  bf16_t* myT = smem + wave * 8192;  // EPI4: 64 cols x 128 rows, XOR-swizzled
#pragma unroll
  for (int m = 0; m < 8; ++m) {
#pragma unroll
    for (int n = 0; n < 4; ++n) {
#pragma unroll
      for (int u = 0; u < 4; ++u) {
        const int gr = m0 + wmr + m * 16 + rr + u;
        const int gc = n0 + wnc + n * 16 + cc;
        float v = acc[m][n][u];
        const size_t idx = (size_t)gr * 4096 + gc;
        if constexpr (EPI == 0) {
          Cb[idx] = __float2bfloat16(v);
        } else if constexpr (EPI == 2) {
          v = __bfloat162float(X0[idx]) + fmaxf(v, 0.f) * rowm[gr];
          Cb[idx] = __float2bfloat16(v);
        } else {  // EPI 4: relu*mask, write C and stage C^T in LDS
          v = fmaxf(v, 0.f) * rowm[gr];
          const bf16_t bv = __float2bfloat16(v);
          Cb[idx] = bv;
          const int lrow = m * 16 + rr + u;  // 0..127
          const int lcol = n * 16 + cc;      // 0..63
          myT[lcol * 128 + (lrow ^ ((lcol & 15) << 3))] = bv;
        }
      }
    }
  }
  if constexpr (EPI == 4) {
    bf16_t* CT = (bf16_t*)AUX;
#pragma unroll
    for (int i = 0; i < 16; ++i) {
      const int chunkid = i * 64 + lane;  // 0..1023
      const int lcol = chunkid >> 4;      // 0..63
      const int a8 = chunkid & 15;        // token chunk
      const int lbase = lcol * 128 + ((a8 * 8) ^ ((lcol & 15) << 3));
      short8 vv = *(const short8*)(myT + lbase);
      *(short8*)(CT + (size_t)(n0 + wnc + lcol) * 4096 + (m0 + wmr) + a8 * 8) =
          vv;
    }
  }
}

// ---------------------------------------------------------------- smalls ----
__global__ void att_kernel(const bf16_t* __restrict__ x,
                           const float* __restrict__ aw,
                           const float* __restrict__ ab,
                           float* __restrict__ satt) {
  const int row = blockIdx.x, tid = threadIdx.x;
  float s = 0.f;
  const bf16_t* xr = x + (size_t)row * 4096 + tid * 16;
#pragma unroll
  for (int h = 0; h < 2; ++h) {
    short8 v = *(const short8*)(xr + h * 8);
#pragma unroll
    for (int j = 0; j < 8; ++j) {
      union { unsigned int u; float f; } cv;
      cv.u = ((unsigned int)(unsigned short)v[j]) << 16;
      s += cv.f * aw[tid * 16 + h * 8 + j];
    }
  }
  __shared__ float red[256];
  red[tid] = s;
  __syncthreads();
  for (int st = 128; st > 0; st >>= 1) {
    if (tid < st) red[tid] += red[tid + st];
    __syncthreads();
  }
  if (tid == 0) satt[row] = 1.f / (1.f + expf(-(red[0] + ab[0])));
}

__global__ void final_kernel(const float* __restrict__ pS,
                             const float* __restrict__ pM,
                             const float* __restrict__ pw,
                             const float* __restrict__ pb,
                             float* __restrict__ out) {
  const int b = blockIdx.x, tid = threadIdx.x;
  float a[20];
#pragma unroll
  for (int k = 0; k < 20; ++k) a[k] = 0.f;
  for (int c = tid; c < 4096; c += 256) {
    const size_t i0 = (size_t)(2 * b) * 4096 + c;
    const size_t i1 = (size_t)(2 * b + 1) * 4096 + c;
    const float s = pS[i0] + pS[i1];
    const float mx = fmaxf(pM[i0], pM[i1]);
    const float v = s * mx;
#pragma unroll
    for (int k = 0; k < 20; ++k) a[k] += v * pw[c * 20 + k];
  }
  __shared__ float red[256][20];
#pragma unroll
  for (int k = 0; k < 20; ++k) red[tid][k] = a[k];
  __syncthreads();
  for (int st = 128; st > 0; st >>= 1) {
    if (tid < st)
      for (int k = 0; k < 20; ++k) red[tid][k] += red[tid + st][k];
    __syncthreads();
  }
  if (tid < 20) out[b * 20 + tid] = red[0][tid] + pb[tid];
}

// ---------------------------------------------------------------- launch ----
extern "C" void kernel_launch(void* const* d_in, const int* in_sizes, int n_in,
                              void* d_out, int out_size, void* d_ws,
                              size_t ws_size, hipStream_t stream) {
  const float* inputs = (const float*)d_in[0];
  const float* adj    = (const float*)d_in[1];
  const float* mask   = (const float*)d_in[2];
  const float* W0     = (const float*)d_in[3];
  const float* W1     = (const float*)d_in[4];
  const float* att_w  = (const float*)d_in[5];
  const float* att_b  = (const float*)d_in[6];
  const float* ln_w   = (const float*)d_in[7];
  const float* ln_b   = (const float*)d_in[8];
  const float* pred_w = (const float*)d_in[9];
  const float* pred_b = (const float*)d_in[10];
  float* out = (float*)d_out;

  const size_t MB32 = (size_t)32 * 1024 * 1024;
  char* ws = (char*)d_ws;
  bf16_t* SLOT0 = (bf16_t*)(ws);             // XT -> x0T -> x
  bf16_t* SLOT1 = (bf16_t*)(ws + MB32);      // W0T -> W1T -> ln_wT
  bf16_t* SLOT2 = (bf16_t*)(ws + 2 * MB32);  // adjb
  bf16_t* SLOT3 = (bf16_t*)(ws + 3 * MB32);  // S0T -> S1T
  bf16_t* SLOT4 = (bf16_t*)(ws + 4 * MB32);  // x0
  float*  pS    = (float*)(ws + 5 * MB32);               // [16][4096]
  float*  pM    = (float*)(ws + 5 * MB32 + 256 * 1024);  // [16][4096]
  float*  satt  = (float*)(ws + 5 * MB32 + 512 * 1024);  // [4096]

  const int SMEM = 163840;  // ring-5 x 2 operands x 16KB
  (void)hipFuncSetAttribute((const void*)gemm_nt<0>,
                            hipFuncAttributeMaxDynamicSharedMemorySize, SMEM);
  (void)hipFuncSetAttribute((const void*)gemm_nt<2>,
                            hipFuncAttributeMaxDynamicSharedMemorySize, SMEM);
  (void)hipFuncSetAttribute((const void*)gemm_nt<3>,
                            hipFuncAttributeMaxDynamicSharedMemorySize, SMEM);
  (void)hipFuncSetAttribute((const void*)gemm_nt<4>,
                            hipFuncAttributeMaxDynamicSharedMemorySize, SMEM);

  const dim3 gT(64, 64);

  // M1: S0T = XT (.) W0T
  transpose_f32_bf16<<<gT, 256, 0, stream>>>(inputs, SLOT0);
  transpose_f32_bf16<<<gT, 256, 0, stream>>>(W0, SLOT1);
  convert_f32_to_bf16<<<16384, 256, 0, stream>>>(adj, SLOT2);
  gemm_nt<0><<<256, 512, SMEM, stream>>>(SLOT0, SLOT1, SLOT3, nullptr, nullptr,
                                         nullptr, nullptr, nullptr);
  // M2: x0 = relu(adjb (.) S0T) * mask[row]; fused x0T write
  gemm_nt<4><<<256, 512, SMEM, stream>>>(SLOT2, SLOT3, SLOT4, SLOT0, nullptr,
                                         mask, nullptr, nullptr);
  // W1T
  transpose_f32_bf16<<<gT, 256, 0, stream>>>(W1, SLOT1);
  // M3: S1T = x0T (.) W1T
  gemm_nt<0><<<256, 512, SMEM, stream>>>(SLOT0, SLOT1, SLOT3, nullptr, nullptr,
                                         nullptr, nullptr, nullptr);
  // M4: x = x0 + relu(adjb (.) S1T) * mask[row]
  gemm_nt<2><<<256, 512, SMEM, stream>>>(SLOT2, SLOT3, SLOT0, nullptr, SLOT4,
                                         mask, nullptr, nullptr);
  // soft_att from x
  att_kernel<<<4096, 256, 0, stream>>>(SLOT0, att_w, att_b, satt);
  // ln_wT
  transpose_f32_bf16<<<gT, 256, 0, stream>>>(ln_w, SLOT1);
  // M5 fused with pool partials: per-block column sum/max of gated h
  gemm_nt<3><<<256, 512, SMEM, stream>>>(SLOT0, SLOT1, pS, pM, nullptr,
                                         mask, satt, ln_b);
  // out[b] = ((sum0+sum1)*(max(max0,max1))) @ pred_w + pred_b
  final_kernel<<<8, 256, 0, stream>>>(pS, pM, pred_w, pred_b, out);
}